// Round 4
// baseline (530.132 us; speedup 1.0000x reference)
//
#include <hip/hip_runtime.h>
#include <hip/hip_bf16.h>

// Problem constants
#define BB 4
#define SS 1024
#define DD 1024
#define HH 16
#define DKH 64
#define EPS_LN 1e-6f

#define M_ROWS 4096   // B*S
#define KK 2048       // concatenated complex K (re|im)

typedef float  floatx4 __attribute__((ext_vector_type(4)));
typedef short  shortx8 __attribute__((ext_vector_type(8)));
#define MFMA16(a, b, c) __builtin_amdgcn_mfma_f32_16x16x32_bf16(a, b, c, 0, 0, 0)

// pack two floats into one u32 of 2 bf16 (low = first) via single HW op (RNE)
__device__ __forceinline__ unsigned pk2(float lo, float hi) {
    unsigned u;
    asm("v_cvt_pk_bf16_f32 %0, %1, %2" : "=v"(u) : "v"(lo), "v"(hi));
    return u;
}

// float -> bf16 (RNE) via the same HW op
__device__ __forceinline__ ushort f2b(float x) {
    return (ushort)(pk2(x, x) & 0xffffu);
}

// negate a bf16x8 fragment (flip sign bits)
__device__ __forceinline__ shortx8 negf(shortx8 x) {
    shortx8 r;
    #pragma unroll
    for (int i = 0; i < 8; ++i) r[i] = (short)(x[i] ^ (short)0x8000);
    return r;
}

// per-32-bit-word [lo=vr, hi=-vi] -> [lo=vi, hi=vr]  (rotate16 + flip lo sign)
__device__ __forceinline__ shortx8 vswap(shortx8 v) {
    union { shortx8 s; unsigned u[4]; } a, b;
    a.s = v;
    #pragma unroll
    for (int i = 0; i < 4; ++i) {
        const unsigned w = a.u[i];
        b.u[i] = ((w >> 16) | (w << 16)) ^ 0x00008000u;
    }
    return b.s;
}

// async global->LDS, 16 bytes per lane (lane-contiguous LDS layout required)
__device__ __forceinline__ void gl16(const void* g, void* l) {
    __builtin_amdgcn_global_load_lds(
        (const __attribute__((address_space(1))) unsigned int*)g,
        (__attribute__((address_space(3))) unsigned int*)l, 16, 0, 0);
}

// ---------------------------------------------------------------------------
// pack_x: [4096][1024] fp32 pair -> [4096][2048] bf16  (row = [re | im])
// ---------------------------------------------------------------------------
__global__ __launch_bounds__(256) void pack_x(
    const float* __restrict__ qr, const float* __restrict__ qi,
    const float* __restrict__ kr, const float* __restrict__ ki,
    const float* __restrict__ vr, const float* __restrict__ vi,
    ushort* __restrict__ Xq, ushort* __restrict__ Xk, ushort* __restrict__ Xv)
{
    const int t = blockIdx.y;
    const float* pr = t == 0 ? qr : t == 1 ? kr : vr;
    const float* pi = t == 0 ? qi : t == 1 ? ki : vi;
    ushort* X = t == 0 ? Xq : t == 1 ? Xk : Xv;
    const int idx = blockIdx.x * 256 + threadIdx.x;
    const int row = idx >> 8, c4 = (idx & 255) * 4;
    float4 a = *(const float4*)(pr + (size_t)row * 1024 + c4);
    float4 b = *(const float4*)(pi + (size_t)row * 1024 + c4);
    ushort4 ua; ua.x = f2b(a.x); ua.y = f2b(a.y); ua.z = f2b(a.z); ua.w = f2b(a.w);
    ushort4 ub; ub.x = f2b(b.x); ub.y = f2b(b.y); ub.z = f2b(b.z); ub.w = f2b(b.w);
    *(ushort4*)(X + (size_t)row * KK + c4)        = ua;
    *(ushort4*)(X + (size_t)row * KK + 1024 + c4) = ub;
}

// ---------------------------------------------------------------------------
// pack_w: [1024][1024] fp32 pair -> [2048][2048] bf16
//   row n       = [ wr[n] | -wi[n] ]   (produces Yr)
//   row 1024+n  = [ wi[n] |  wr[n] ]   (produces Yi)
// ---------------------------------------------------------------------------
__global__ __launch_bounds__(256) void pack_w(
    const float* __restrict__ ar, const float* __restrict__ ai,
    const float* __restrict__ br, const float* __restrict__ bi,
    const float* __restrict__ cr, const float* __restrict__ ci,
    const float* __restrict__ dr, const float* __restrict__ di,
    ushort* __restrict__ Bq, ushort* __restrict__ Bk,
    ushort* __restrict__ Bv, ushort* __restrict__ Bf)
{
    const int t = blockIdx.y;
    const float* wr = t == 0 ? ar : t == 1 ? br : t == 2 ? cr : dr;
    const float* wi = t == 0 ? ai : t == 1 ? bi : t == 2 ? ci : di;
    ushort* Bo = t == 0 ? Bq : t == 1 ? Bk : t == 2 ? Bv : Bf;
    const int idx = blockIdx.x * 256 + threadIdx.x;
    const int n = idx >> 8, c4 = (idx & 255) * 4;
    float4 a = *(const float4*)(wr + (size_t)n * 1024 + c4);
    float4 b = *(const float4*)(wi + (size_t)n * 1024 + c4);
    ushort4 ua; ua.x = f2b(a.x);  ua.y = f2b(a.y);  ua.z = f2b(a.z);  ua.w = f2b(a.w);
    ushort4 ub; ub.x = f2b(b.x);  ub.y = f2b(b.y);  ub.z = f2b(b.z);  ub.w = f2b(b.w);
    ushort4 un; un.x = f2b(-b.x); un.y = f2b(-b.y); un.z = f2b(-b.z); un.w = f2b(-b.w);
    *(ushort4*)(Bo + (size_t)n * KK + c4)                 = ua;
    *(ushort4*)(Bo + (size_t)n * KK + 1024 + c4)          = un;
    *(ushort4*)(Bo + (size_t)(1024 + n) * KK + c4)        = ub;
    *(ushort4*)(Bo + (size_t)(1024 + n) * KK + 1024 + c4) = ua;
}

// ---------------------------------------------------------------------------
// bf16 MFMA GEMM, m201 template: 256x256 tile, BK=64, 8 waves (2M x 4N).
// C[M, N=2048] = A[M,2048] . B[N,2048]^T
// Per-wave output 128x64 (8 m-frags x 4 n-frags), 64 MFMA / wave / K-tile.
// LDS 128 KiB: 2 dbuf x (A 32K + B 32K), 1 block/CU.
// 4 sub-phases per K-tile (one output quadrant each, 16 MFMA):
//   P1: ds a(m-lo) 8 + b(n-lo) 4 -> Q00   P2: ds b(n-hi) 4 -> Q01
//   P3: ds a(m-hi) 8 -> Q11               P4: stage tile t+2, Q10 (regs only)
// Counted vmcnt(8) once per K-tile (tile t+1's 8 gl16 stay in flight across
// all barriers); vmcnt(0) only at the last tile. Stage of t+2 into buffer
// (t&1) is safe in P4: P3's trailing barrier comes after every wave's
// lgkmcnt(0), so no ds_read of that buffer is pending block-wide.
// Chunk-XOR LDS swizzle (linear dest + inverse-swizzled gl16 source +
// swizzled ds_read): b128 reads measured conflict-free.
// Epilogue modes (fragment-major packs so attn loads are lane-coalesced):
//   0: Q frag pack   3: K frag pack   1: V frag pack [vr,-vi]
//   2: fp32 out + residual
// ---------------------------------------------------------------------------
#define GBM 256
#define GBN 256
#define GBK 64

// stage one K-tile (64 KB) into buffer P: 8 x gl16 per thread
#define STAGE8(P, T) do {                                                     \
    const ushort* ga_ = gA + (size_t)(T) * GBK;                               \
    const ushort* gb_ = gB + (size_t)(T) * GBK;                               \
    ushort* la_ = &As[P][st8];                                                \
    ushort* lb_ = &Bs[P][st8];                                                \
    _Pragma("unroll")                                                         \
    for (int s_ = 0; s_ < 4; ++s_)                                            \
        gl16(ga_ + (size_t)s_ * 64 * KK, la_ + s_ * 4096);                    \
    _Pragma("unroll")                                                         \
    for (int s_ = 0; s_ < 4; ++s_)                                            \
        gl16(gb_ + (size_t)s_ * 64 * KK, lb_ + s_ * 4096);                    \
} while (0)

#define TILE8(P, VM, DOSTAGE) do {                                            \
    asm volatile("s_waitcnt vmcnt(" #VM ")" ::: "memory");                    \
    __builtin_amdgcn_s_barrier();                                             \
    /* P1: Q00 */                                                             \
    _Pragma("unroll")                                                         \
    for (int j = 0; j < 4; ++j) {                                             \
        const int ra_ = aoff + j * 1024;                                      \
        aA[j][0] = *(const shortx8*)&As[P][ra_ + ca0];                        \
        aA[j][1] = *(const shortx8*)&As[P][ra_ + ca1];                        \
    }                                                                         \
    _Pragma("unroll")                                                         \
    for (int j = 0; j < 2; ++j) {                                             \
        const int rb_ = boff + j * 1024;                                      \
        bA[j][0] = *(const shortx8*)&Bs[P][rb_ + ca0];                        \
        bA[j][1] = *(const shortx8*)&Bs[P][rb_ + ca1];                        \
    }                                                                         \
    asm volatile("s_waitcnt lgkmcnt(0)" ::: "memory");                        \
    __builtin_amdgcn_sched_barrier(0);                                        \
    __builtin_amdgcn_s_setprio(1);                                            \
    _Pragma("unroll")                                                         \
    for (int j = 0; j < 4; ++j)                                               \
        _Pragma("unroll")                                                     \
        for (int n_ = 0; n_ < 2; ++n_) {                                      \
            acc[j][n_] = MFMA16(aA[j][0], bA[n_][0], acc[j][n_]);             \
            acc[j][n_] = MFMA16(aA[j][1], bA[n_][1], acc[j][n_]);             \
        }                                                                     \
    __builtin_amdgcn_s_setprio(0);                                            \
    __builtin_amdgcn_s_barrier();                                             \
    /* P2: Q01 */                                                             \
    _Pragma("unroll")                                                         \
    for (int j = 0; j < 2; ++j) {                                             \
        const int rb_ = boff + 2048 + j * 1024;                               \
        bB[j][0] = *(const shortx8*)&Bs[P][rb_ + ca0];                        \
        bB[j][1] = *(const shortx8*)&Bs[P][rb_ + ca1];                        \
    }                                                                         \
    asm volatile("s_waitcnt lgkmcnt(0)" ::: "memory");                        \
    __builtin_amdgcn_sched_barrier(0);                                        \
    __builtin_amdgcn_s_setprio(1);                                            \
    _Pragma("unroll")                                                         \
    for (int j = 0; j < 4; ++j)                                               \
        _Pragma("unroll")                                                     \
        for (int n_ = 0; n_ < 2; ++n_) {                                      \
            acc[j][2 + n_] = MFMA16(aA[j][0], bB[n_][0], acc[j][2 + n_]);     \
            acc[j][2 + n_] = MFMA16(aA[j][1], bB[n_][1], acc[j][2 + n_]);     \
        }                                                                     \
    __builtin_amdgcn_s_setprio(0);                                            \
    __builtin_amdgcn_s_barrier();                                             \
    /* P3: Q11 */                                                             \
    _Pragma("unroll")                                                         \
    for (int j = 0; j < 4; ++j) {                                             \
        const int ra_ = aoff + 4096 + j * 1024;                               \
        aA[j][0] = *(const shortx8*)&As[P][ra_ + ca0];                        \
        aA[j][1] = *(const shortx8*)&As[P][ra_ + ca1];                        \
    }                                                                         \
    asm volatile("s_waitcnt lgkmcnt(0)" ::: "memory");                        \
    __builtin_amdgcn_sched_barrier(0);                                        \
    __builtin_amdgcn_s_setprio(1);                                            \
    _Pragma("unroll")                                                         \
    for (int j = 0; j < 4; ++j)                                               \
        _Pragma("unroll")                                                     \
        for (int n_ = 0; n_ < 2; ++n_) {                                      \
            acc[4 + j][2 + n_] = MFMA16(aA[j][0], bB[n_][0], acc[4 + j][2 + n_]); \
            acc[4 + j][2 + n_] = MFMA16(aA[j][1], bB[n_][1], acc[4 + j][2 + n_]); \
        }                                                                     \
    __builtin_amdgcn_s_setprio(0);                                            \
    __builtin_amdgcn_s_barrier();                                             \
    /* P4: stage t+2 into freed buffer, Q10 from registers */                 \
    if (DOSTAGE) STAGE8(P, kt + 2);                                           \
    __builtin_amdgcn_s_setprio(1);                                            \
    _Pragma("unroll")                                                         \
    for (int j = 0; j < 4; ++j)                                               \
        _Pragma("unroll")                                                     \
        for (int n_ = 0; n_ < 2; ++n_) {                                      \
            acc[4 + j][n_] = MFMA16(aA[j][0], bA[n_][0], acc[4 + j][n_]);     \
            acc[4 + j][n_] = MFMA16(aA[j][1], bA[n_][1], acc[4 + j][n_]);     \
        }                                                                     \
    __builtin_amdgcn_s_setprio(0);                                            \
    ++kt;                                                                     \
} while (0)

__device__ __forceinline__ void bgemm_body(
    const ushort* __restrict__ A, const ushort* __restrict__ Bm,
    void* __restrict__ out0, void* __restrict__ out1,
    const float* __restrict__ resr, const float* __restrict__ resi,
    float scale, int mode, int bx, int by)
{
    __shared__ __align__(16) ushort As[2][GBM * GBK];   // 2 x 32 KiB
    __shared__ __align__(16) ushort Bs[2][GBN * GBK];   // 2 x 32 KiB

    const int t = threadIdx.x;
    const int lane = t & 63, wave = t >> 6;
    const int l15 = lane & 15, quad = lane >> 4;
    const int wm = (wave >> 2) * 128;       // wave M offset (2 M-groups)
    const int wn = (wave & 3) * 64;         // wave N offset (4 N-groups)
    const int m0 = by * GBM, n0 = bx * GBN;

    // staging: thread t covers 16B chunk; row = t>>3 (+64/sweep),
    // LDS chunk slot c' = t&7 holds global chunk c = c' ^ (row&7)
    const int srow = t >> 3;
    const int schk = (t & 7) ^ (srow & 7);
    const int st8  = t * 8;
    const ushort* gA = A  + (size_t)(m0 + srow) * KK + schk * 8;
    const ushort* gB = Bm + (size_t)(n0 + srow) * KK + schk * 8;

    // ds_read chunk offsets (ushorts): logical chunk (ks*4+quad) ^ (row&7)
    const int rm  = l15 & 7;
    const int ca0 = ((quad)     ^ rm) * 8;
    const int ca1 = ((4 + quad) ^ rm) * 8;
    const int aoff = (wm + l15) * 64;
    const int boff = (wn + l15) * 64;

    floatx4 acc[8][4];
    #pragma unroll
    for (int fm = 0; fm < 8; ++fm)
        #pragma unroll
        for (int fn = 0; fn < 4; ++fn)
            acc[fm][fn] = (floatx4){0.f, 0.f, 0.f, 0.f};

    shortx8 aA[4][2], bA[2][2], bB[2][2];

    STAGE8(0, 0);
    STAGE8(1, 1);

    int kt = 0;
    for (int i = 0; i < 15; ++i) {      // tiles 0..29, staging tiles 2..31
        TILE8(0, 8, 1);
        TILE8(1, 8, 1);
    }
    TILE8(0, 8, 0);                     // tile 30 (tile 31 stays in flight)
    TILE8(1, 0, 0);                     // tile 31, drain

    // Epilogue. C layout: col = lane&15, row = quad*4 + reg.
    #pragma unroll
    for (int fm = 0; fm < 8; ++fm) {
        #pragma unroll
        for (int fn = 0; fn < 4; ++fn) {
            #pragma unroll
            for (int r = 0; r < 4; ++r) {
                const int m = m0 + wm + fm * 16 + quad * 4 + r;
                const int n = n0 + wn + fn * 16 + l15;
                const float v = acc[fm][fn][r] * scale;
                const int nn = n & 1023;
                const int hh = nn >> 6;
                const int bb = m >> 10, s = m & 1023;
                if (mode == 0) {           // Q fragment pack (32-row tiles)
                    const int dk = (n < 1024 ? 0 : 64) + (nn & 63);
                    const int tq = s >> 5, row = s & 31;
                    ushort* Qb = (ushort*)out0 +
                        ((size_t)(bb * HH + hh) * 32 + tq) * 4096;
                    const int off = ((row >> 4) * 4 + (dk >> 5)) * 512 +
                                    ((dk >> 3) & 3) * 128 + (row & 15) * 8 + (dk & 7);
                    Qb[off] = f2b(v);
                } else if (mode == 3) {    // K fragment pack (64-row tiles)
                    const int dk = (n < 1024 ? 0 : 64) + (nn & 63);
                    const int tt = s >> 6, row = s & 63;
                    ushort* Kb = (ushort*)out0 +
                        ((size_t)(bb * HH + hh) * 16 + tt) * 8192;
                    const int off = ((row >> 4) * 4 + (dk >> 5)) * 512 +
                                    ((dk >> 3) & 3) * 128 + (row & 15) * 8 + (dk & 7);
                    Kb[off] = f2b(v);
                } else if (mode == 1) {    // V fragment pack, interleaved [vr,-vi]
                    const int dv = nn & 63;
                    const int c = 2 * s + (n < 1024 ? 0 : 1);
                    ushort* Vb = (ushort*)out0 + (size_t)(bb * HH + hh) * 131072;
                    const int off = (((c >> 7) * 4 + (dv >> 4)) * 4 + ((c >> 5) & 3)) * 512 +
                                    ((c >> 3) & 3) * 128 + (dv & 15) * 8 + (c & 7);
                    Vb[off] = f2b(n < 1024 ? v : -v);
                } else {                   // fc: fp32 out + residual
                    const size_t off = (size_t)m * 1024 + nn;
                    if (n < 1024) ((float*)out0)[off] = v + resr[off];
                    else          ((float*)out1)[off] = v + resi[off];
                }
            }
        }
    }
}

// merged QKV projection GEMMs: blockIdx.z selects {Q, K, V}.
// V output lives in d_out scratch (no aliasing with any input of this grid).
__global__ __launch_bounds__(512) void bgemm_qkv(
    const ushort* __restrict__ Xq, const ushort* __restrict__ Xk,
    const ushort* __restrict__ Xv,
    const ushort* __restrict__ Bq, const ushort* __restrict__ Bk,
    const ushort* __restrict__ Bv,
    ushort* __restrict__ qpk, ushort* __restrict__ kpk,
    ushort* __restrict__ Vneg)
{
    const int z = blockIdx.z;
    const ushort* A  = z == 0 ? Xq : z == 1 ? Xk : Xv;
    const ushort* Bm = z == 0 ? Bq : z == 1 ? Bk : Bv;
    void* o0 = z == 0 ? (void*)qpk : z == 1 ? (void*)kpk : (void*)Vneg;
    const float sc = z == 0 ? 0.125f : 1.0f;
    const int mode = z == 0 ? 0 : z == 1 ? 3 : 1;
    bgemm_body(A, Bm, o0, nullptr, nullptr, nullptr, sc, mode,
               blockIdx.x, blockIdx.y);
}

// fc GEMM: fp32 out + residual
__global__ __launch_bounds__(512) void bgemm_fc(
    const ushort* __restrict__ A, const ushort* __restrict__ Bm,
    float* __restrict__ fr, float* __restrict__ fi,
    const float* __restrict__ resr, const float* __restrict__ resi)
{
    bgemm_body(A, Bm, fr, fi, resr, resi, 1.0f, 2, blockIdx.x, blockIdx.y);
}

// ---------------------------------------------------------------------------
// Cooperative MFMA attention + exact streamed MagMinMaxNorm, TK=64/iteration.
//   o = (A - mn*P)/(mx - mn);  A = sum attn*v,  P = sum (attn/|attn|)*v
// All Q/K/V global loads are lane-coalesced (fragment-major packs).
// K register double-buffered; V loaded at iteration top; Vswap derived
// in-register. Per-iteration barrier is lgkmcnt(0)-only. LDS A/P ping-pong,
// XOR-swizzled. 1-D grid, XCD-contiguous swizzle.
// Output: bf16 pack xo[m][2048] = [o_r (h*64+dv) | o_i].
// ---------------------------------------------------------------------------
#define SWZ(row, col) (((row) << 5) + ((col) ^ (((row) & 7) << 2)))

__device__ __forceinline__ void loadK(shortx8 (&K)[2][4], const ushort* kfb,
                                      int t, int kt_w) {
    #pragma unroll
    for (int kt2 = 0; kt2 < 2; ++kt2)
        #pragma unroll
        for (int f = 0; f < 4; ++f)
            K[kt2][f] = *(const shortx8*)(kfb + t * 8192 +
                                          ((kt_w * 2 + kt2) * 4 + f) * 512);
}

__device__ __forceinline__ void loadVn(shortx8 (&V)[4], const ushort* vfb,
                                       int t, int wave) {
    #pragma unroll
    for (int f = 0; f < 4; ++f)
        V[f] = *(const shortx8*)(vfb + ((t * 4 + wave) * 4 + f) * 512);
}

#define ATTN_ITER(IT, NX, KC, KN)                                             \
  {                                                                           \
    loadVn(V_, vfb, (IT), wave);                                              \
    const int p_ = (IT) & 1;                                                  \
    unsigned* Ab = Abuf[p_][kt_w];                                            \
    unsigned* Pb = Pbuf[p_][kt_w];                                            \
    floatx4 cr[2], ci[2];                                                     \
    _Pragma("unroll")                                                         \
    for (int kt2 = 0; kt2 < 2; ++kt2) {                                       \
      floatx4 r_ = (floatx4){0.f, 0.f, 0.f, 0.f};                             \
      floatx4 i_ = (floatx4){0.f, 0.f, 0.f, 0.f};                             \
      r_ = MFMA16(Aq0, KC[kt2][0], r_); r_ = MFMA16(Aq1, KC[kt2][1], r_);     \
      r_ = MFMA16(Nq2, KC[kt2][2], r_); r_ = MFMA16(Nq3, KC[kt2][3], r_);     \
      i_ = MFMA16(Aq2, KC[kt2][0], i_); i_ = MFMA16(Aq3, KC[kt2][1], i_);     \
      i_ = MFMA16(Aq0, KC[kt2][2], i_); i_ = MFMA16(Aq1, KC[kt2][3], i_);     \
      cr[kt2] = r_; ci[kt2] = i_;                                             \
    }                                                                         \
    loadK(KN, kfb, (NX), kt_w);                                               \
    _Pragma("unroll")                                                         \
    for (int kt2 = 0; kt2 < 2; ++kt2) {                                       \
      _Pragma("unroll")                                                       \
      for (int r = 0; r < 4; ++r) {                                           \
        const float ar = cr[kt2][r], ai = ci[kt2][r];                         \
        const float s2 = fmaf(ar, ar, ai * ai);                               \
        const float irm = s2 > 0.f ? rsqrtf(s2) : 0.f;                        \
        const float mag = s2 * irm;                                           \
        rmn[r] = fminf(rmn[r], mag);                                          \
        rmx[r] = fmaxf(rmx[r], mag);                                          \
        const int row_ = qt_w * 16 + quad * 4 + r;                            \
        const int w_ = SWZ(row_, kt2 * 16 + l15);                             \
        Ab[w_] = pk2(ar, ai);                                                 \
        Pb[w_] = pk2(ar * irm, ai * irm);                                     \
      }                                                                       \
    }                                                                         \
    asm volatile("s_waitcnt lgkmcnt(0)" ::: "memory");                        \
    __builtin_amdgcn_s_barrier();                                             \
    const shortx8 Vs0 = vswap(V_[0]), Vs1 = vswap(V_[1]);                     \
    const shortx8 Vs2 = vswap(V_[2]), Vs3 = vswap(V_[3]);                     \
    const unsigned* A0 = Abuf[p_][0];                                         \
    const unsigned* A1 = Abuf[p_][1];                                         \
    const unsigned* P0 = Pbuf[p_][0];                                         \
    const unsigned* P1 = Pbuf[p_][1];                                         \
    __builtin_amdgcn_s_setprio(1);                                            \
    _Pragma("unroll")                                                         \
    for (int q2 = 0; q2 < 2; ++q2) {                                          \
      const int row_ = q2 * 16 + l15;                                         \
      const int rb_ = row_ * 32, rm_ = (row_ & 7) << 2;                       \
      const int c0_ = rb_ + ((quad * 4) ^ rm_);                               \
      const int c1_ = rb_ + ((16 + quad * 4) ^ rm_);                          \
      shortx8 Af0 = *(const shortx8*)&A0[c0_];                                \
      shortx8 Af1 = *(const shortx8*)&A0[c1_];                                \
      shortx8 Af2 = *(const shortx8*)&A1[c0_];                                \
      shortx8 Af3 = *(const shortx8*)&A1[c1_];                                \
      shortx8 Pf0 = *(const shortx8*)&P0[c0_];                                \
      shortx8 Pf1 = *(const shortx8*)&P0[c1_];                                \
      shortx8 Pf2 = *(const shortx8*)&P1[c0_];                                \
      shortx8 Pf3 = *(const shortx8*)&P1[c1_];                                \
      acc[q2][0] = MFMA16(Af0, V_[0], acc[q2][0]);                            \
      acc[q2][0] = MFMA16(Af1, V_[1], acc[q2][0]);                            \
      acc[q2][0] = MFMA16(Af2, V_[2], acc[q2][0]);                            \
      acc[q2][0] = MFMA16(Af3, V_[3], acc[q2][0]);                            \
      acc[q2][1] = MFMA16(Af0, Vs0, acc[q2][1]);                              \
      acc[q2][1] = MFMA16(Af1, Vs1, acc[q2][1]);                              \
      acc[q2][1] = MFMA16(Af2, Vs2, acc[q2][1]);                              \
      acc[q2][1] = MFMA16(Af3, Vs3, acc[q2][1]);                              \
      acc[q2][2] = MFMA16(Pf0, V_[0], acc[q2][2]);                            \
      acc[q2][2] = MFMA16(Pf1, V_[1], acc[q2][2]);                            \
      acc[q2][2] = MFMA16(Pf2, V_[2], acc[q2][2]);                            \
      acc[q2][2] = MFMA16(Pf3, V_[3], acc[q2][2]);                            \
      acc[q2][3] = MFMA16(Pf0, Vs0, acc[q2][3]);                              \
      acc[q2][3] = MFMA16(Pf1, Vs1, acc[q2][3]);                              \
      acc[q2][3] = MFMA16(Pf2, Vs2, acc[q2][3]);                              \
      acc[q2][3] = MFMA16(Pf3, Vs3, acc[q2][3]);                              \
    }                                                                         \
    __builtin_amdgcn_s_setprio(0);                                            \
  }

__global__ __launch_bounds__(256) void attn_mfma(
    const ushort* __restrict__ qpk, const ushort* __restrict__ kpk,
    const ushort* __restrict__ vn, ushort* __restrict__ xo)
{
    __shared__ unsigned Abuf[2][2][32 * 32];   // [pingpong][k-half][32q x 32k]
    __shared__ unsigned Pbuf[2][2][32 * 32];
    __shared__ unsigned mnb[32], mxb[32];

    const int tid  = threadIdx.x;
    const int wave = tid >> 6, lane = tid & 63;
    const int l15  = lane & 15, quad = lane >> 4;
    const int qt_w = wave & 1, kt_w = wave >> 1;

    // XCD-contiguous swizzle: XCD x gets swz range [x*256, x*256+256) ->
    // 8 whole (b,h) groups per XCD (2048 blocks, 8 XCDs, qt fastest).
    const int swz = (blockIdx.x & 7) * 256 + (blockIdx.x >> 3);
    const int qt = swz & 31, hb = swz >> 5;
    const int h = hb & 15, b = hb >> 4;
    const size_t qrow0 = (size_t)b * SS + (size_t)qt * 32;

    if (tid < 32) { mnb[tid] = 0x7f800000u; mxb[tid] = 0u; }

    // Q fragments (fragment-major pack: coalesced), pre-negated imag copies
    const ushort* qfb = qpk + ((size_t)(b * HH + h) * 32 + qt) * 4096 + lane * 8;
    shortx8 Aq0 = *(const shortx8*)(qfb + (qt_w * 4 + 0) * 512);
    shortx8 Aq1 = *(const shortx8*)(qfb + (qt_w * 4 + 1) * 512);
    shortx8 Aq2 = *(const shortx8*)(qfb + (qt_w * 4 + 2) * 512);
    shortx8 Aq3 = *(const shortx8*)(qfb + (qt_w * 4 + 3) * 512);
    shortx8 Nq2 = negf(Aq2), Nq3 = negf(Aq3);

    const ushort* kfb = kpk + (size_t)(b * HH + h) * 131072 + lane * 8;
    const ushort* vfb = vn  + (size_t)(b * HH + h) * 131072 + lane * 8;

    floatx4 acc[2][4];   // [q-half][Ar,Ai,Pr,Pi]
    #pragma unroll
    for (int q2 = 0; q2 < 2; ++q2)
        #pragma unroll
        for (int j = 0; j < 4; ++j)
            acc[q2][j] = (floatx4){0.f, 0.f, 0.f, 0.f};
    float rmn[4] = {1e30f, 1e30f, 1e30f, 1e30f};
    float rmx[4] = {0.f, 0.f, 0.f, 0.f};

    shortx8 KA[2][4], KB[2][4], V_[4];
    loadK(KA, kfb, 0, kt_w);

    for (int it = 0; it < 16; it += 2) {
        ATTN_ITER(it,     it + 1,        KA, KB);
        ATTN_ITER(it + 1, (it + 2) & 15, KB, KA);
    }

    // ---- per-row min/max: 16-lane shuffle, then cross-wave LDS atomics ----
    #pragma unroll
    for (int r = 0; r < 4; ++r) {
        float mn = rmn[r], mx = rmx[r];
        #pragma unroll
        for (int o = 1; o < 16; o <<= 1) {
            mn = fminf(mn, __shfl_xor(mn, o));
            mx = fmaxf(mx, __shfl_xor(mx, o));
        }
        if (l15 == 0) {
            const int q = qt_w * 16 + quad * 4 + r;
            atomicMin(&mnb[q], __float_as_uint(mn));   // mag >= 0: bits monotone
            atomicMax(&mxb[q], __float_as_uint(mx));
        }
    }
    __syncthreads();

    // ---- epilogue: o = (A - mn*P)/(mx - mn) -> bf16 pack ----
    #pragma unroll
    for (int q2 = 0; q2 < 2; ++q2) {
        #pragma unroll
        for (int r = 0; r < 4; ++r) {
            const int q = q2 * 16 + quad * 4 + r;
            const float mn = __uint_as_float(mnb[q]);
            const float mx = __uint_as_float(mxb[q]);
            const float d = mx - mn;
            const float invd = d > 0.f ? 1.f / d : 0.f;
            const float vr_ = (acc[q2][0][r] - mn * acc[q2][2][r]) * invd;
            const float vi_ = (acc[q2][1][r] - mn * acc[q2][3][r]) * invd;
            const size_t row = (qrow0 + q) * KK + h * 64 + wave * 16 + l15;
            xo[row]        = f2b(vr_);
            xo[row + 1024] = f2b(vi_);
        }
    }
}

// ---------------------------------------------------------------------------
// Complex covariance-whitening layernorm, one wave per (b,s) row.
// ---------------------------------------------------------------------------
__global__ __launch_bounds__(256) void ln_kernel(
    const float* __restrict__ xr, const float* __restrict__ xi,
    const float* __restrict__ g_rr, const float* __restrict__ g_ri,
    const float* __restrict__ g_ii,
    const float* __restrict__ b_r, const float* __restrict__ b_i,
    float* __restrict__ out)
{
    const int lane = threadIdx.x & 63;
    const int wave = threadIdx.x >> 6;
    const int row  = blockIdx.x * 4 + wave;
    const float* pr = xr + (size_t)row * DD;
    const float* pi = xi + (size_t)row * DD;

    float r[16], im[16];
    float sr = 0.f, si = 0.f;
    #pragma unroll
    for (int j = 0; j < 16; ++j) {
        r[j]  = pr[lane + 64*j];
        im[j] = pi[lane + 64*j];
        sr += r[j]; si += im[j];
    }
    #pragma unroll
    for (int o = 32; o; o >>= 1) { sr += __shfl_xor(sr, o); si += __shfl_xor(si, o); }
    const float mr = sr * (1.f / DD), mi = si * (1.f / DD);

    float srr = 0.f, sii = 0.f, sri = 0.f;
    #pragma unroll
    for (int j = 0; j < 16; ++j) {
        const float a = r[j] - mr, c = im[j] - mi;
        srr = fmaf(a, a, srr); sii = fmaf(c, c, sii); sri = fmaf(a, c, sri);
    }
    #pragma unroll
    for (int o = 32; o; o >>= 1) {
        srr += __shfl_xor(srr, o); sii += __shfl_xor(sii, o); sri += __shfl_xor(sri, o);
    }
    const float Vrr = srr * (1.f / DD) + EPS_LN;
    const float Vii = sii * (1.f / DD) + EPS_LN;
    const float Vri = sri * (1.f / DD);
    const float s  = sqrtf(Vrr * Vii - Vri * Vri);
    const float t  = sqrtf(Vrr + Vii + 2.f * s);
    const float inv = 1.f / (s * t);
    const float Wrr = (Vii + s) * inv;
    const float Wii = (Vrr + s) * inv;
    const float Wri = -Vri * inv;

    #pragma unroll
    for (int j = 0; j < 16; ++j) {
        const int d = lane + 64*j;
        const float a = r[j] - mr, c = im[j] - mi;
        const float or_ = Wrr * a + Wri * c;
        const float oi_ = Wri * a + Wii * c;
        out[(size_t)row * DD + d] = g_rr[d]*or_ + g_ri[d]*oi_ + b_r[d];
        out[(size_t)(M_ROWS) * DD + (size_t)row * DD + d] = g_ri[d]*or_ + g_ii[d]*oi_ + b_i[d];
    }
}

// ---------------------------------------------------------------------------
extern "C" void kernel_launch(void* const* d_in, const int* in_sizes, int n_in,
                              void* d_out, int out_size, void* d_ws, size_t ws_size,
                              hipStream_t stream) {
    const float* q_r  = (const float*)d_in[0];
    const float* q_i  = (const float*)d_in[1];
    const float* k_r  = (const float*)d_in[2];
    const float* k_i  = (const float*)d_in[3];
    const float* v_r  = (const float*)d_in[4];
    const float* v_i  = (const float*)d_in[5];
    const float* wq_r = (const float*)d_in[6];
    const float* wq_i = (const float*)d_in[7];
    const float* wk_r = (const float*)d_in[8];
    const float* wk_i = (const float*)d_in[9];
    const float* wv_r = (const float*)d_in[10];
    const float* wv_i = (const float*)d_in[11];
    const float* fc_r = (const float*)d_in[12];
    const float* fc_i = (const float*)d_in[13];
    const float* g_rr = (const float*)d_in[14];
    const float* g_ri = (const float*)d_in[15];
    const float* g_ii = (const float*)d_in[16];
    const float* b_r  = (const float*)d_in[17];
    const float* b_i  = (const float*)d_in[18];
    float* out = (float*)d_out;

    // Workspace: 7 units of 16 MiB = 112 MiB.
    float* ws = (float*)d_ws;
    const size_t NE = (size_t)M_ROWS * 1024;        // 4M floats = 16 MiB
    ushort* Xq   = (ushort*)(ws + 0 * NE);          // u0
    ushort* Xk   = (ushort*)(ws + 1 * NE);          // u1
    ushort* Xv   = (ushort*)(ws + 2 * NE);          // u2; later xo
    ushort* qpk  = (ushort*)(ws + 3 * NE);          // u3; later fr
    ushort* kpk  = (ushort*)(ws + 4 * NE);          // u4; later fi
    ushort* Bq   = (ushort*)(ws + 5 * NE);          // u5 lo
    ushort* Bk   = Bq + (size_t)KK * KK;            // u5 hi
    ushort* Bv   = (ushort*)(ws + 6 * NE);          // u6 lo
    ushort* Bf   = Bv + (size_t)KK * KK;            // u6 hi
    ushort* Vneg = (ushort*)d_out;                  // d_out scratch (32 MiB, dead until ln)
    ushort* xo   = (ushort*)(ws + 2 * NE);          // aliases dead Xv
    float*  fr   = ws + 3 * NE;                     // aliases dead qpk
    float*  fi   = ws + 4 * NE;                     // aliases dead kpk

    // bf16 operand packing
    pack_x<<<dim3(4096, 3), 256, 0, stream>>>(q_r, q_i, k_r, k_i, v_r, v_i, Xq, Xk, Xv);
    pack_w<<<dim3(1024, 4), 256, 0, stream>>>(wq_r, wq_i, wk_r, wk_i, wv_r, wv_i,
                                              fc_r, fc_i, Bq, Bk, Bv, Bf);

    // merged QKV projections (q gets 1/sqrt(DK) folded in): 384 blocks,
    // 256x256 tiles. gridDim.x == 8 == NXCD -> bx-column per XCD (B-panel
    // stationary in its L2).
    bgemm_qkv<<<dim3(KK / GBN, M_ROWS / GBM, 3), 512, 0, stream>>>(
        Xq, Xk, Xv, Bq, Bk, Bv, qpk, kpk, Vneg);

    // cooperative MFMA attention + MagMinMaxNorm -> bf16 [4096][2048] pack
    attn_mfma<<<dim3(2048), 256, 0, stream>>>(qpk, kpk, Vneg, xo);

    // output projection + residual (bf16 MFMA, fp32 out)
    bgemm_fc<<<dim3(KK / GBN, M_ROWS / GBM), 512, 0, stream>>>(xo, Bf, fr, fi, q_r, q_i);

    // complex layernorm -> d_out [2,B,S,D]
    ln_kernel<<<M_ROWS / 4, 256, 0, stream>>>(fr, fi, g_rr, g_ri, g_ii, b_r, b_i, out);
}

// Round 5
// 492.694 us; speedup vs baseline: 1.0760x; 1.0760x over previous
//
#include <hip/hip_runtime.h>
#include <hip/hip_bf16.h>

// Problem constants
#define BB 4
#define SS 1024
#define DD 1024
#define HH 16
#define DKH 64
#define EPS_LN 1e-6f

#define M_ROWS 4096   // B*S
#define KK 2048       // concatenated complex K (re|im)

typedef float  floatx4 __attribute__((ext_vector_type(4)));
typedef short  shortx8 __attribute__((ext_vector_type(8)));
#define MFMA16(a, b, c) __builtin_amdgcn_mfma_f32_16x16x32_bf16(a, b, c, 0, 0, 0)

// pack two floats into one u32 of 2 bf16 (low = first) via single HW op (RNE)
__device__ __forceinline__ unsigned pk2(float lo, float hi) {
    unsigned u;
    asm("v_cvt_pk_bf16_f32 %0, %1, %2" : "=v"(u) : "v"(lo), "v"(hi));
    return u;
}

// float -> bf16 (RNE) via the same HW op
__device__ __forceinline__ ushort f2b(float x) {
    return (ushort)(pk2(x, x) & 0xffffu);
}

// negate a bf16x8 fragment (flip sign bits)
__device__ __forceinline__ shortx8 negf(shortx8 x) {
    shortx8 r;
    #pragma unroll
    for (int i = 0; i < 8; ++i) r[i] = (short)(x[i] ^ (short)0x8000);
    return r;
}

// per-32-bit-word [lo=vr, hi=-vi] -> [lo=vi, hi=vr]  (rotate16 + flip lo sign)
__device__ __forceinline__ shortx8 vswap(shortx8 v) {
    union { shortx8 s; unsigned u[4]; } a, b;
    a.s = v;
    #pragma unroll
    for (int i = 0; i < 4; ++i) {
        const unsigned w = a.u[i];
        b.u[i] = ((w >> 16) | (w << 16)) ^ 0x00008000u;
    }
    return b.s;
}

// async global->LDS, 16 bytes per lane (lane-contiguous LDS layout required)
__device__ __forceinline__ void gl16(const void* g, void* l) {
    __builtin_amdgcn_global_load_lds(
        (const __attribute__((address_space(1))) unsigned int*)g,
        (__attribute__((address_space(3))) unsigned int*)l, 16, 0, 0);
}

// ---------------------------------------------------------------------------
// pack_x: [4096][1024] fp32 pair -> [4096][2048] bf16  (row = [re | im])
// ---------------------------------------------------------------------------
__global__ __launch_bounds__(256) void pack_x(
    const float* __restrict__ qr, const float* __restrict__ qi,
    const float* __restrict__ kr, const float* __restrict__ ki,
    const float* __restrict__ vr, const float* __restrict__ vi,
    ushort* __restrict__ Xq, ushort* __restrict__ Xk, ushort* __restrict__ Xv)
{
    const int t = blockIdx.y;
    const float* pr = t == 0 ? qr : t == 1 ? kr : vr;
    const float* pi = t == 0 ? qi : t == 1 ? ki : vi;
    ushort* X = t == 0 ? Xq : t == 1 ? Xk : Xv;
    const int idx = blockIdx.x * 256 + threadIdx.x;
    const int row = idx >> 8, c4 = (idx & 255) * 4;
    float4 a = *(const float4*)(pr + (size_t)row * 1024 + c4);
    float4 b = *(const float4*)(pi + (size_t)row * 1024 + c4);
    ushort4 ua; ua.x = f2b(a.x); ua.y = f2b(a.y); ua.z = f2b(a.z); ua.w = f2b(a.w);
    ushort4 ub; ub.x = f2b(b.x); ub.y = f2b(b.y); ub.z = f2b(b.z); ub.w = f2b(b.w);
    *(ushort4*)(X + (size_t)row * KK + c4)        = ua;
    *(ushort4*)(X + (size_t)row * KK + 1024 + c4) = ub;
}

// ---------------------------------------------------------------------------
// pack_w: [1024][1024] fp32 pair -> [2048][2048] bf16
//   row n       = [ wr[n] | -wi[n] ]   (produces Yr)
//   row 1024+n  = [ wi[n] |  wr[n] ]   (produces Yi)
// ---------------------------------------------------------------------------
__global__ __launch_bounds__(256) void pack_w(
    const float* __restrict__ ar, const float* __restrict__ ai,
    const float* __restrict__ br, const float* __restrict__ bi,
    const float* __restrict__ cr, const float* __restrict__ ci,
    const float* __restrict__ dr, const float* __restrict__ di,
    ushort* __restrict__ Bq, ushort* __restrict__ Bk,
    ushort* __restrict__ Bv, ushort* __restrict__ Bf)
{
    const int t = blockIdx.y;
    const float* wr = t == 0 ? ar : t == 1 ? br : t == 2 ? cr : dr;
    const float* wi = t == 0 ? ai : t == 1 ? bi : t == 2 ? ci : di;
    ushort* Bo = t == 0 ? Bq : t == 1 ? Bk : t == 2 ? Bv : Bf;
    const int idx = blockIdx.x * 256 + threadIdx.x;
    const int n = idx >> 8, c4 = (idx & 255) * 4;
    float4 a = *(const float4*)(wr + (size_t)n * 1024 + c4);
    float4 b = *(const float4*)(wi + (size_t)n * 1024 + c4);
    ushort4 ua; ua.x = f2b(a.x);  ua.y = f2b(a.y);  ua.z = f2b(a.z);  ua.w = f2b(a.w);
    ushort4 ub; ub.x = f2b(b.x);  ub.y = f2b(b.y);  ub.z = f2b(b.z);  ub.w = f2b(b.w);
    ushort4 un; un.x = f2b(-b.x); un.y = f2b(-b.y); un.z = f2b(-b.z); un.w = f2b(-b.w);
    *(ushort4*)(Bo + (size_t)n * KK + c4)                 = ua;
    *(ushort4*)(Bo + (size_t)n * KK + 1024 + c4)          = un;
    *(ushort4*)(Bo + (size_t)(1024 + n) * KK + c4)        = ub;
    *(ushort4*)(Bo + (size_t)(1024 + n) * KK + 1024 + c4) = ua;
}

// ---------------------------------------------------------------------------
// bf16 MFMA GEMM, software-pipelined: 256x128 tile, BK=32, 8 waves (4M x 2N).
// C[M, N=2048] = A[M,2048] . B[N,2048]^T
// Per-wave output 64x64: 16 MFMA + 8 ds_read_b128 per K-step.
// LDS = ring of 4 K-step slots (A 16K + B 8K each) = 96 KiB, 1 block/CU.
// Pipeline body(j), one barrier per step, MFMA always from registers:
//   ds_read frags(j+1)  |  stage 3 gl16 (step j+4, slot j&3)
//   sched_barrier; setprio(1); 16 MFMA (frags j, in regs); setprio(0)
//   lgkmcnt(0); vmcnt(6); s_barrier
// Safety: stage at body(j) overwrites slot j&3, last read at body(j-1) and
// retired by its lgkmcnt(0) before its barrier. vmcnt(6) completes step j+2's
// 3 loads (issued at body(j-2)) -> slot resident for body(j+1)'s ds_read.
// BK=32 row-major needs no swizzle (uniform 8 words/bank = b128 floor).
// Grids are exact multiples of 256 CUs: qkv 16x16x3 = 768, fc 16x16 = 256.
// Epilogue modes (fragment-major packs so attn loads are lane-coalesced):
//   0: Q frag pack   3: K frag pack   1: V frag pack [vr,-vi]
//   2: fp32 out + residual
// ---------------------------------------------------------------------------
#define GBM 256
#define GBN 128
#define GBK 32
#define ASLOT (GBM * GBK)   // 8192 ushorts = 16 KiB
#define BSLOT (GBN * GBK)   // 4096 ushorts = 8 KiB

// stage step S (3 x gl16 per thread): A rows t>>2 and t>>2+128, B row t>>2
#define GSTG(S) do {                                                          \
    const int sl_ = (S) & 3;                                                  \
    const ushort* ga_ = gA0 + (S) * GBK;                                      \
    const ushort* gb_ = gB0 + (S) * GBK;                                      \
    ushort* la_ = AsAll + sl_ * ASLOT + t8;                                   \
    ushort* lb_ = BsAll + sl_ * BSLOT + t8;                                   \
    gl16(ga_, la_);                                                           \
    gl16(ga_ + 128 * KK, la_ + 4096);                                         \
    gl16(gb_, lb_);                                                           \
} while (0)

// read MFMA fragments for step J into register sets AN/BN
#define GRD(J, AN, BN) do {                                                   \
    const ushort* As_ = AsAll + ((J) & 3) * ASLOT + ard;                      \
    const ushort* Bs_ = BsAll + ((J) & 3) * BSLOT + brd;                      \
    AN[0] = *(const shortx8*)(As_);                                           \
    AN[1] = *(const shortx8*)(As_ + 16 * GBK);                                \
    AN[2] = *(const shortx8*)(As_ + 32 * GBK);                                \
    AN[3] = *(const shortx8*)(As_ + 48 * GBK);                                \
    BN[0] = *(const shortx8*)(Bs_);                                           \
    BN[1] = *(const shortx8*)(Bs_ + 16 * GBK);                                \
    BN[2] = *(const shortx8*)(Bs_ + 32 * GBK);                                \
    BN[3] = *(const shortx8*)(Bs_ + 48 * GBK);                                \
} while (0)

#define GBODY(J, VM, DOSTAGE, DOREAD, AC, BC, AN, BN) do {                    \
    if (DOREAD) GRD((J) + 1, AN, BN);                                         \
    if (DOSTAGE) GSTG((J) + 4);                                               \
    __builtin_amdgcn_sched_barrier(0);                                        \
    __builtin_amdgcn_s_setprio(1);                                            \
    _Pragma("unroll")                                                         \
    for (int f_ = 0; f_ < 4; ++f_)                                            \
        _Pragma("unroll")                                                     \
        for (int g_ = 0; g_ < 4; ++g_)                                        \
            acc[f_][g_] = MFMA16(AC[f_], BC[g_], acc[f_][g_]);                \
    __builtin_amdgcn_s_setprio(0);                                            \
    __builtin_amdgcn_sched_barrier(0);                                        \
    asm volatile("s_waitcnt lgkmcnt(0)" ::: "memory");                        \
    asm volatile("s_waitcnt vmcnt(" #VM ")" ::: "memory");                    \
    __builtin_amdgcn_s_barrier();                                             \
} while (0)

__device__ __forceinline__ void bgemm_body(
    const ushort* __restrict__ A, const ushort* __restrict__ Bm,
    void* __restrict__ out0, void* __restrict__ out1,
    const float* __restrict__ resr, const float* __restrict__ resi,
    float scale, int mode, int bx, int by)
{
    __shared__ __align__(16) ushort AsAll[4 * ASLOT];   // 64 KiB
    __shared__ __align__(16) ushort BsAll[4 * BSLOT];   // 32 KiB

    const int t = threadIdx.x;
    const int lane = t & 63, wave = t >> 6;
    const int l15 = lane & 15, quad = lane >> 4;
    const int wm = (wave >> 1) * 64;        // 4 M-wave groups
    const int wn = (wave & 1) * 64;         // 2 N-wave groups
    const int m0 = by * GBM, n0 = bx * GBN;

    // staging pointers: thread t covers 16B chunk t (A also +512)
    const int t8 = t * 8;
    const ushort* gA0 = A  + (size_t)(m0 + (t >> 2)) * KK + (t & 3) * 8;
    const ushort* gB0 = Bm + (size_t)(n0 + (t >> 2)) * KK + (t & 3) * 8;

    // ds_read fragment base offsets (ushorts)
    const int ard = (wm + l15) * GBK + quad * 8;
    const int brd = (wn + l15) * GBK + quad * 8;

    floatx4 acc[4][4];
    #pragma unroll
    for (int f = 0; f < 4; ++f)
        #pragma unroll
        for (int g = 0; g < 4; ++g)
            acc[f][g] = (floatx4){0.f, 0.f, 0.f, 0.f};

    shortx8 aE[4], bE[4], aO[4], bO[4];

    // prologue: stage steps 0-3 (12 loads); wait steps 0,1; read frags(0)
    GSTG(0); GSTG(1); GSTG(2); GSTG(3);
    asm volatile("s_waitcnt vmcnt(6)" ::: "memory");
    __builtin_amdgcn_s_barrier();
    GRD(0, aE, bE);
    asm volatile("s_waitcnt lgkmcnt(0)" ::: "memory");
    __builtin_amdgcn_s_barrier();   // all waves' frag-0 reads retired

    for (int j = 0; j < 60; j += 2) {
        GBODY(j,     6, 1, 1, aE, bE, aO, bO);
        GBODY(j + 1, 6, 1, 1, aO, bO, aE, bE);
    }
    GBODY(60, 3, 0, 1, aE, bE, aO, bO);
    GBODY(61, 0, 0, 1, aO, bO, aE, bE);
    GBODY(62, 0, 0, 1, aE, bE, aO, bO);
    GBODY(63, 0, 0, 0, aO, bO, aE, bE);

    // Epilogue. C layout: col = lane&15, row = quad*4 + reg.
    #pragma unroll
    for (int fm = 0; fm < 4; ++fm) {
        #pragma unroll
        for (int fn = 0; fn < 4; ++fn) {
            #pragma unroll
            for (int r = 0; r < 4; ++r) {
                const int m = m0 + wm + fm * 16 + quad * 4 + r;
                const int n = n0 + wn + fn * 16 + l15;
                const float v = acc[fm][fn][r] * scale;
                const int nn = n & 1023;
                const int hh = nn >> 6;
                const int bb = m >> 10, s = m & 1023;
                if (mode == 0) {           // Q fragment pack (32-row tiles)
                    const int dk = (n < 1024 ? 0 : 64) + (nn & 63);
                    const int tq = s >> 5, row = s & 31;
                    ushort* Qb = (ushort*)out0 +
                        ((size_t)(bb * HH + hh) * 32 + tq) * 4096;
                    const int off = ((row >> 4) * 4 + (dk >> 5)) * 512 +
                                    ((dk >> 3) & 3) * 128 + (row & 15) * 8 + (dk & 7);
                    Qb[off] = f2b(v);
                } else if (mode == 3) {    // K fragment pack (64-row tiles)
                    const int dk = (n < 1024 ? 0 : 64) + (nn & 63);
                    const int tt = s >> 6, row = s & 63;
                    ushort* Kb = (ushort*)out0 +
                        ((size_t)(bb * HH + hh) * 16 + tt) * 8192;
                    const int off = ((row >> 4) * 4 + (dk >> 5)) * 512 +
                                    ((dk >> 3) & 3) * 128 + (row & 15) * 8 + (dk & 7);
                    Kb[off] = f2b(v);
                } else if (mode == 1) {    // V fragment pack, interleaved [vr,-vi]
                    const int dv = nn & 63;
                    const int c = 2 * s + (n < 1024 ? 0 : 1);
                    ushort* Vb = (ushort*)out0 + (size_t)(bb * HH + hh) * 131072;
                    const int off = (((c >> 7) * 4 + (dv >> 4)) * 4 + ((c >> 5) & 3)) * 512 +
                                    ((c >> 3) & 3) * 128 + (dv & 15) * 8 + (c & 7);
                    Vb[off] = f2b(n < 1024 ? v : -v);
                } else {                   // fc: fp32 out + residual
                    const size_t off = (size_t)m * 1024 + nn;
                    if (n < 1024) ((float*)out0)[off] = v + resr[off];
                    else          ((float*)out1)[off] = v + resi[off];
                }
            }
        }
    }
}

// merged QKV projection GEMMs: blockIdx.z selects {Q, K, V}.
// V output lives in d_out scratch (no aliasing with any input of this grid).
__global__ __launch_bounds__(512, 2) void bgemm_qkv(
    const ushort* __restrict__ Xq, const ushort* __restrict__ Xk,
    const ushort* __restrict__ Xv,
    const ushort* __restrict__ Bq, const ushort* __restrict__ Bk,
    const ushort* __restrict__ Bv,
    ushort* __restrict__ qpk, ushort* __restrict__ kpk,
    ushort* __restrict__ Vneg)
{
    const int z = blockIdx.z;
    const ushort* A  = z == 0 ? Xq : z == 1 ? Xk : Xv;
    const ushort* Bm = z == 0 ? Bq : z == 1 ? Bk : Bv;
    void* o0 = z == 0 ? (void*)qpk : z == 1 ? (void*)kpk : (void*)Vneg;
    const float sc = z == 0 ? 0.125f : 1.0f;
    const int mode = z == 0 ? 0 : z == 1 ? 3 : 1;
    bgemm_body(A, Bm, o0, nullptr, nullptr, nullptr, sc, mode,
               blockIdx.x, blockIdx.y);
}

// fc GEMM: fp32 out + residual
__global__ __launch_bounds__(512, 2) void bgemm_fc(
    const ushort* __restrict__ A, const ushort* __restrict__ Bm,
    float* __restrict__ fr, float* __restrict__ fi,
    const float* __restrict__ resr, const float* __restrict__ resi)
{
    bgemm_body(A, Bm, fr, fi, resr, resi, 1.0f, 2, blockIdx.x, blockIdx.y);
}

// ---------------------------------------------------------------------------
// Cooperative MFMA attention + exact streamed MagMinMaxNorm, TK=64/iteration.
//   o = (A - mn*P)/(mx - mn);  A = sum attn*v,  P = sum (attn/|attn|)*v
// All Q/K/V global loads are lane-coalesced (fragment-major packs).
// K register double-buffered; V loaded at iteration top; Vswap derived
// in-register. Per-iteration barrier is lgkmcnt(0)-only. LDS A/P ping-pong,
// XOR-swizzled. 1-D grid, XCD-contiguous swizzle.
// Output: bf16 pack xo[m][2048] = [o_r (h*64+dv) | o_i].
// ---------------------------------------------------------------------------
#define SWZ(row, col) (((row) << 5) + ((col) ^ (((row) & 7) << 2)))

__device__ __forceinline__ void loadK(shortx8 (&K)[2][4], const ushort* kfb,
                                      int t, int kt_w) {
    #pragma unroll
    for (int kt2 = 0; kt2 < 2; ++kt2)
        #pragma unroll
        for (int f = 0; f < 4; ++f)
            K[kt2][f] = *(const shortx8*)(kfb + t * 8192 +
                                          ((kt_w * 2 + kt2) * 4 + f) * 512);
}

__device__ __forceinline__ void loadVn(shortx8 (&V)[4], const ushort* vfb,
                                       int t, int wave) {
    #pragma unroll
    for (int f = 0; f < 4; ++f)
        V[f] = *(const shortx8*)(vfb + ((t * 4 + wave) * 4 + f) * 512);
}

#define ATTN_ITER(IT, NX, KC, KN)                                             \
  {                                                                           \
    loadVn(V_, vfb, (IT), wave);                                              \
    const int p_ = (IT) & 1;                                                  \
    unsigned* Ab = Abuf[p_][kt_w];                                            \
    unsigned* Pb = Pbuf[p_][kt_w];                                            \
    floatx4 cr[2], ci[2];                                                     \
    _Pragma("unroll")                                                         \
    for (int kt2 = 0; kt2 < 2; ++kt2) {                                       \
      floatx4 r_ = (floatx4){0.f, 0.f, 0.f, 0.f};                             \
      floatx4 i_ = (floatx4){0.f, 0.f, 0.f, 0.f};                             \
      r_ = MFMA16(Aq0, KC[kt2][0], r_); r_ = MFMA16(Aq1, KC[kt2][1], r_);     \
      r_ = MFMA16(Nq2, KC[kt2][2], r_); r_ = MFMA16(Nq3, KC[kt2][3], r_);     \
      i_ = MFMA16(Aq2, KC[kt2][0], i_); i_ = MFMA16(Aq3, KC[kt2][1], i_);     \
      i_ = MFMA16(Aq0, KC[kt2][2], i_); i_ = MFMA16(Aq1, KC[kt2][3], i_);     \
      cr[kt2] = r_; ci[kt2] = i_;                                             \
    }                                                                         \
    loadK(KN, kfb, (NX), kt_w);                                               \
    _Pragma("unroll")                                                         \
    for (int kt2 = 0; kt2 < 2; ++kt2) {                                       \
      _Pragma("unroll")                                                       \
      for (int r = 0; r < 4; ++r) {                                           \
        const float ar = cr[kt2][r], ai = ci[kt2][r];                         \
        const float s2 = fmaf(ar, ar, ai * ai);                               \
        const float irm = s2 > 0.f ? rsqrtf(s2) : 0.f;                        \
        const float mag = s2 * irm;                                           \
        rmn[r] = fminf(rmn[r], mag);                                          \
        rmx[r] = fmaxf(rmx[r], mag);                                          \
        const int row_ = qt_w * 16 + quad * 4 + r;                            \
        const int w_ = SWZ(row_, kt2 * 16 + l15);                             \
        Ab[w_] = pk2(ar, ai);                                                 \
        Pb[w_] = pk2(ar * irm, ai * irm);                                     \
      }                                                                       \
    }                                                                         \
    asm volatile("s_waitcnt lgkmcnt(0)" ::: "memory");                        \
    __builtin_amdgcn_s_barrier();                                             \
    const shortx8 Vs0 = vswap(V_[0]), Vs1 = vswap(V_[1]);                     \
    const shortx8 Vs2 = vswap(V_[2]), Vs3 = vswap(V_[3]);                     \
    const unsigned* A0 = Abuf[p_][0];                                         \
    const unsigned* A1 = Abuf[p_][1];                                         \
    const unsigned* P0 = Pbuf[p_][0];                                         \
    const unsigned* P1 = Pbuf[p_][1];                                         \
    __builtin_amdgcn_s_setprio(1);                                            \
    _Pragma("unroll")                                                         \
    for (int q2 = 0; q2 < 2; ++q2) {                                          \
      const int row_ = q2 * 16 + l15;                                         \
      const int rb_ = row_ * 32, rm_ = (row_ & 7) << 2;                       \
      const int c0_ = rb_ + ((quad * 4) ^ rm_);                               \
      const int c1_ = rb_ + ((16 + quad * 4) ^ rm_);                          \
      shortx8 Af0 = *(const shortx8*)&A0[c0_];                                \
      shortx8 Af1 = *(const shortx8*)&A0[c1_];                                \
      shortx8 Af2 = *(const shortx8*)&A1[c0_];                                \
      shortx8 Af3 = *(const shortx8*)&A1[c1_];                                \
      shortx8 Pf0 = *(const shortx8*)&P0[c0_];                                \
      shortx8 Pf1 = *(const shortx8*)&P0[c1_];                                \
      shortx8 Pf2 = *(const shortx8*)&P1[c0_];                                \
      shortx8 Pf3 = *(const shortx8*)&P1[c1_];                                \
      acc[q2][0] = MFMA16(Af0, V_[0], acc[q2][0]);                            \
      acc[q2][0] = MFMA16(Af1, V_[1], acc[q2][0]);                            \
      acc[q2][0] = MFMA16(Af2, V_[2], acc[q2][0]);                            \
      acc[q2][0] = MFMA16(Af3, V_[3], acc[q2][0]);                            \
      acc[q2][1] = MFMA16(Af0, Vs0, acc[q2][1]);                              \
      acc[q2][1] = MFMA16(Af1, Vs1, acc[q2][1]);                              \
      acc[q2][1] = MFMA16(Af2, Vs2, acc[q2][1]);                              \
      acc[q2][1] = MFMA16(Af3, Vs3, acc[q2][1]);                              \
      acc[q2][2] = MFMA16(Pf0, V_[0], acc[q2][2]);                            \
      acc[q2][2] = MFMA16(Pf1, V_[1], acc[q2][2]);                            \
      acc[q2][2] = MFMA16(Pf2, V_[2], acc[q2][2]);                            \
      acc[q2][2] = MFMA16(Pf3, V_[3], acc[q2][2]);                            \
      acc[q2][3] = MFMA16(Pf0, Vs0, acc[q2][3]);                              \
      acc[q2][3] = MFMA16(Pf1, Vs1, acc[q2][3]);                              \
      acc[q2][3] = MFMA16(Pf2, Vs2, acc[q2][3]);                              \
      acc[q2][3] = MFMA16(Pf3, Vs3, acc[q2][3]);                              \
    }                                                                         \
    __builtin_amdgcn_s_setprio(0);                                            \
  }

__global__ __launch_bounds__(256) void attn_mfma(
    const ushort* __restrict__ qpk, const ushort* __restrict__ kpk,
    const ushort* __restrict__ vn, ushort* __restrict__ xo)
{
    __shared__ unsigned Abuf[2][2][32 * 32];   // [pingpong][k-half][32q x 32k]
    __shared__ unsigned Pbuf[2][2][32 * 32];
    __shared__ unsigned mnb[32], mxb[32];

    const int tid  = threadIdx.x;
    const int wave = tid >> 6, lane = tid & 63;
    const int l15  = lane & 15, quad = lane >> 4;
    const int qt_w = wave & 1, kt_w = wave >> 1;

    // XCD-contiguous swizzle: XCD x gets swz range [x*256, x*256+256) ->
    // 8 whole (b,h) groups per XCD (2048 blocks, 8 XCDs, qt fastest).
    const int swz = (blockIdx.x & 7) * 256 + (blockIdx.x >> 3);
    const int qt = swz & 31, hb = swz >> 5;
    const int h = hb & 15, b = hb >> 4;
    const size_t qrow0 = (size_t)b * SS + (size_t)qt * 32;

    if (tid < 32) { mnb[tid] = 0x7f800000u; mxb[tid] = 0u; }

    // Q fragments (fragment-major pack: coalesced), pre-negated imag copies
    const ushort* qfb = qpk + ((size_t)(b * HH + h) * 32 + qt) * 4096 + lane * 8;
    shortx8 Aq0 = *(const shortx8*)(qfb + (qt_w * 4 + 0) * 512);
    shortx8 Aq1 = *(const shortx8*)(qfb + (qt_w * 4 + 1) * 512);
    shortx8 Aq2 = *(const shortx8*)(qfb + (qt_w * 4 + 2) * 512);
    shortx8 Aq3 = *(const shortx8*)(qfb + (qt_w * 4 + 3) * 512);
    shortx8 Nq2 = negf(Aq2), Nq3 = negf(Aq3);

    const ushort* kfb = kpk + (size_t)(b * HH + h) * 131072 + lane * 8;
    const ushort* vfb = vn  + (size_t)(b * HH + h) * 131072 + lane * 8;

    floatx4 acc[2][4];   // [q-half][Ar,Ai,Pr,Pi]
    #pragma unroll
    for (int q2 = 0; q2 < 2; ++q2)
        #pragma unroll
        for (int j = 0; j < 4; ++j)
            acc[q2][j] = (floatx4){0.f, 0.f, 0.f, 0.f};
    float rmn[4] = {1e30f, 1e30f, 1e30f, 1e30f};
    float rmx[4] = {0.f, 0.f, 0.f, 0.f};

    shortx8 KA[2][4], KB[2][4], V_[4];
    loadK(KA, kfb, 0, kt_w);

    for (int it = 0; it < 16; it += 2) {
        ATTN_ITER(it,     it + 1,        KA, KB);
        ATTN_ITER(it + 1, (it + 2) & 15, KB, KA);
    }

    // ---- per-row min/max: 16-lane shuffle, then cross-wave LDS atomics ----
    #pragma unroll
    for (int r = 0; r < 4; ++r) {
        float mn = rmn[r], mx = rmx[r];
        #pragma unroll
        for (int o = 1; o < 16; o <<= 1) {
            mn = fminf(mn, __shfl_xor(mn, o));
            mx = fmaxf(mx, __shfl_xor(mx, o));
        }
        if (l15 == 0) {
            const int q = qt_w * 16 + quad * 4 + r;
            atomicMin(&mnb[q], __float_as_uint(mn));   // mag >= 0: bits monotone
            atomicMax(&mxb[q], __float_as_uint(mx));
        }
    }
    __syncthreads();

    // ---- epilogue: o = (A - mn*P)/(mx - mn) -> bf16 pack ----
    #pragma unroll
    for (int q2 = 0; q2 < 2; ++q2) {
        #pragma unroll
        for (int r = 0; r < 4; ++r) {
            const int q = q2 * 16 + quad * 4 + r;
            const float mn = __uint_as_float(mnb[q]);
            const float mx = __uint_as_float(mxb[q]);
            const float d = mx - mn;
            const float invd = d > 0.f ? 1.f / d : 0.f;
            const float vr_ = (acc[q2][0][r] - mn * acc[q2][2][r]) * invd;
            const float vi_ = (acc[q2][1][r] - mn * acc[q2][3][r]) * invd;
            const size_t row = (qrow0 + q) * KK + h * 64 + wave * 16 + l15;
            xo[row]        = f2b(vr_);
            xo[row + 1024] = f2b(vi_);
        }
    }
}

// ---------------------------------------------------------------------------
// Complex covariance-whitening layernorm, one wave per (b,s) row.
// ---------------------------------------------------------------------------
__global__ __launch_bounds__(256) void ln_kernel(
    const float* __restrict__ xr, const float* __restrict__ xi,
    const float* __restrict__ g_rr, const float* __restrict__ g_ri,
    const float* __restrict__ g_ii,
    const float* __restrict__ b_r, const float* __restrict__ b_i,
    float* __restrict__ out)
{
    const int lane = threadIdx.x & 63;
    const int wave = threadIdx.x >> 6;
    const int row  = blockIdx.x * 4 + wave;
    const float* pr = xr + (size_t)row * DD;
    const float* pi = xi + (size_t)row * DD;

    float r[16], im[16];
    float sr = 0.f, si = 0.f;
    #pragma unroll
    for (int j = 0; j < 16; ++j) {
        r[j]  = pr[lane + 64*j];
        im[j] = pi[lane + 64*j];
        sr += r[j]; si += im[j];
    }
    #pragma unroll
    for (int o = 32; o; o >>= 1) { sr += __shfl_xor(sr, o); si += __shfl_xor(si, o); }
    const float mr = sr * (1.f / DD), mi = si * (1.f / DD);

    float srr = 0.f, sii = 0.f, sri = 0.f;
    #pragma unroll
    for (int j = 0; j < 16; ++j) {
        const float a = r[j] - mr, c = im[j] - mi;
        srr = fmaf(a, a, srr); sii = fmaf(c, c, sii); sri = fmaf(a, c, sri);
    }
    #pragma unroll
    for (int o = 32; o; o >>= 1) {
        srr += __shfl_xor(srr, o); sii += __shfl_xor(sii, o); sri += __shfl_xor(sri, o);
    }
    const float Vrr = srr * (1.f / DD) + EPS_LN;
    const float Vii = sii * (1.f / DD) + EPS_LN;
    const float Vri = sri * (1.f / DD);
    const float s  = sqrtf(Vrr * Vii - Vri * Vri);
    const float t  = sqrtf(Vrr + Vii + 2.f * s);
    const float inv = 1.f / (s * t);
    const float Wrr = (Vii + s) * inv;
    const float Wii = (Vrr + s) * inv;
    const float Wri = -Vri * inv;

    #pragma unroll
    for (int j = 0; j < 16; ++j) {
        const int d = lane + 64*j;
        const float a = r[j] - mr, c = im[j] - mi;
        const float or_ = Wrr * a + Wri * c;
        const float oi_ = Wri * a + Wii * c;
        out[(size_t)row * DD + d] = g_rr[d]*or_ + g_ri[d]*oi_ + b_r[d];
        out[(size_t)(M_ROWS) * DD + (size_t)row * DD + d] = g_ri[d]*or_ + g_ii[d]*oi_ + b_i[d];
    }
}

// ---------------------------------------------------------------------------
extern "C" void kernel_launch(void* const* d_in, const int* in_sizes, int n_in,
                              void* d_out, int out_size, void* d_ws, size_t ws_size,
                              hipStream_t stream) {
    const float* q_r  = (const float*)d_in[0];
    const float* q_i  = (const float*)d_in[1];
    const float* k_r  = (const float*)d_in[2];
    const float* k_i  = (const float*)d_in[3];
    const float* v_r  = (const float*)d_in[4];
    const float* v_i  = (const float*)d_in[5];
    const float* wq_r = (const float*)d_in[6];
    const float* wq_i = (const float*)d_in[7];
    const float* wk_r = (const float*)d_in[8];
    const float* wk_i = (const float*)d_in[9];
    const float* wv_r = (const float*)d_in[10];
    const float* wv_i = (const float*)d_in[11];
    const float* fc_r = (const float*)d_in[12];
    const float* fc_i = (const float*)d_in[13];
    const float* g_rr = (const float*)d_in[14];
    const float* g_ri = (const float*)d_in[15];
    const float* g_ii = (const float*)d_in[16];
    const float* b_r  = (const float*)d_in[17];
    const float* b_i  = (const float*)d_in[18];
    float* out = (float*)d_out;

    // Workspace: 7 units of 16 MiB = 112 MiB.
    float* ws = (float*)d_ws;
    const size_t NE = (size_t)M_ROWS * 1024;        // 4M floats = 16 MiB
    ushort* Xq   = (ushort*)(ws + 0 * NE);          // u0
    ushort* Xk   = (ushort*)(ws + 1 * NE);          // u1
    ushort* Xv   = (ushort*)(ws + 2 * NE);          // u2; later xo
    ushort* qpk  = (ushort*)(ws + 3 * NE);          // u3; later fr
    ushort* kpk  = (ushort*)(ws + 4 * NE);          // u4; later fi
    ushort* Bq   = (ushort*)(ws + 5 * NE);          // u5 lo
    ushort* Bk   = Bq + (size_t)KK * KK;            // u5 hi
    ushort* Bv   = (ushort*)(ws + 6 * NE);          // u6 lo
    ushort* Bf   = Bv + (size_t)KK * KK;            // u6 hi
    ushort* Vneg = (ushort*)d_out;                  // d_out scratch (32 MiB, dead until ln)
    ushort* xo   = (ushort*)(ws + 2 * NE);          // aliases dead Xv
    float*  fr   = ws + 3 * NE;                     // aliases dead qpk
    float*  fi   = ws + 4 * NE;                     // aliases dead kpk

    // bf16 operand packing
    pack_x<<<dim3(4096, 3), 256, 0, stream>>>(q_r, q_i, k_r, k_i, v_r, v_i, Xq, Xk, Xv);
    pack_w<<<dim3(1024, 4), 256, 0, stream>>>(wq_r, wq_i, wk_r, wk_i, wv_r, wv_i,
                                              fc_r, fc_i, Bq, Bk, Bv, Bf);

    // merged QKV projections (q gets 1/sqrt(DK) folded in): 256x128 tiles,
    // 768 blocks = 3.0 x 256 CUs exactly. linear%8 = bx%8 -> B-panel per XCD.
    bgemm_qkv<<<dim3(KK / GBN, M_ROWS / GBM, 3), 512, 0, stream>>>(
        Xq, Xk, Xv, Bq, Bk, Bv, qpk, kpk, Vneg);

    // cooperative MFMA attention + MagMinMaxNorm -> bf16 [4096][2048] pack
    attn_mfma<<<dim3(2048), 256, 0, stream>>>(qpk, kpk, Vneg, xo);

    // output projection + residual (bf16 MFMA, fp32 out): 256 blocks exactly
    bgemm_fc<<<dim3(KK / GBN, M_ROWS / GBM), 512, 0, stream>>>(xo, Bf, fr, fi, q_r, q_i);

    // complex layernorm -> d_out [2,B,S,D]
    ln_kernel<<<M_ROWS / 4, 256, 0, stream>>>(fr, fi, g_rr, g_ri, g_ii, b_r, b_i, out);
}